// Round 6
// baseline (134.835 us; speedup 1.0000x reference)
//
#include <hip/hip_runtime.h>

// SNN loss, MI355X. Round 6: 256x256 tile, 8-wave phase-split K-loop with
// T2 granule-swizzle + T4 counted-vmcnt + T5 setprio (the proven quadrant).
//  k_stats/k_stats2: global std (ddof=1) -> inv_std (folded into c2)
//  k_norm:           raw x -> bf16 (ws), raw row sqn (fp32)
//  k_main:           upper-tri 256x256 MFMA tiles of x·x^T (528 blocks);
//                    LDS 64KB double-buffered, swizzled, per-tile 2 phases,
//                    dual-sided fused masked logsumexp epilogue
//  k_rows/k_final:   combine partials per row, mean, negate

#define NROW 8192
#define NDIM 512
#define BM   256
#define BK   32
#define NKT  (NDIM / BK)           // 16 K-tiles
#define NT   (NROW / BM)           // 32 tiles per dim
#define NBLK (NT * (NT + 1) / 2)   // 528 upper-tri blocks

typedef __attribute__((ext_vector_type(8))) short bf16x8;
typedef __attribute__((ext_vector_type(4))) float f32x4;

#define NEG_INF (-__builtin_inff())

// ---- workspace layout (bytes) ----
static const size_t WS_PART = 0;                                   // 256*2 doubles
static const size_t WS_SCAL = 4096;                                // inv_std float
static const size_t WS_XB   = 8192;                                // bf16 x: 8M
static const size_t WS_SQN  = WS_XB + (size_t)NROW * NDIM * 2;     // 8192 floats
static const size_t WS_P4   = WS_SQN + (size_t)NROW * 4;           // 32*8192 float4
static const size_t WS_ROWV = WS_P4 + (size_t)NT * NROW * 16;      // 8192 floats

__device__ __forceinline__ unsigned short f2bf(float f) {
    unsigned int u = __float_as_uint(f);      // finite inputs only
    u += 0x7FFFu + ((u >> 16) & 1u);          // round-to-nearest-even
    return (unsigned short)(u >> 16);
}

#define GLD_LDS16(gp, lp) __builtin_amdgcn_global_load_lds( \
    (const __attribute__((address_space(1))) unsigned int*)(gp), \
    (__attribute__((address_space(3))) unsigned int*)(lp), 16, 0, 0)

// ---------------- stats: sum / sumsq ----------------
__global__ __launch_bounds__(256) void k_stats(const float* __restrict__ x,
                                               double* __restrict__ part) {
    int t = blockIdx.x * 256 + threadIdx.x;
    const float4* x4 = (const float4*)x;
    double s = 0.0, ss = 0.0;
    for (int i = t; i < (NROW * NDIM / 4); i += 256 * 256) {
        float4 v = x4[i];
        double a = v.x, b = v.y, c = v.z, d = v.w;
        s  += (a + b) + (c + d);
        ss += (a * a + b * b) + (c * c + d * d);
    }
#pragma unroll
    for (int off = 32; off >= 1; off >>= 1) {
        s  += __shfl_xor(s, off, 64);
        ss += __shfl_xor(ss, off, 64);
    }
    __shared__ double sa[4], sb[4];
    int w = threadIdx.x >> 6, lane = threadIdx.x & 63;
    if (lane == 0) { sa[w] = s; sb[w] = ss; }
    __syncthreads();
    if (threadIdx.x == 0) {
        part[blockIdx.x * 2]     = sa[0] + sa[1] + sa[2] + sa[3];
        part[blockIdx.x * 2 + 1] = sb[0] + sb[1] + sb[2] + sb[3];
    }
}

__global__ __launch_bounds__(256) void k_stats2(const double* __restrict__ part,
                                                float* __restrict__ scal) {
    int t = threadIdx.x;
    double s = part[t * 2], ss = part[t * 2 + 1];
#pragma unroll
    for (int off = 32; off >= 1; off >>= 1) {
        s  += __shfl_xor(s, off, 64);
        ss += __shfl_xor(ss, off, 64);
    }
    __shared__ double sa[4], sb[4];
    int w = t >> 6, lane = t & 63;
    if (lane == 0) { sa[w] = s; sb[w] = ss; }
    __syncthreads();
    if (t == 0) {
        double S = sa[0] + sa[1] + sa[2] + sa[3];
        double SS = sb[0] + sb[1] + sb[2] + sb[3];
        const double N = (double)NROW * (double)NDIM;
        double var = (SS - S * S / N) / (N - 1.0);   // ddof=1
        scal[0] = (float)(1.0 / sqrt(var));          // inv_std
    }
}

// ---------------- raw x -> bf16 + raw row sqn ----------------
__global__ __launch_bounds__(256) void k_norm(const float* __restrict__ x,
                                              unsigned short* __restrict__ xb,
                                              float* __restrict__ sqn) {
    int w = threadIdx.x >> 6, lane = threadIdx.x & 63;
    int row = blockIdx.x * 4 + w;
    const float4* xr = (const float4*)(x + (size_t)row * NDIM);
    ushort4* xo = (ushort4*)(xb + (size_t)row * NDIM);
    float ss = 0.f;
#pragma unroll
    for (int ph = 0; ph < 2; ++ph) {
        float4 v = xr[ph * 64 + lane];
        ss += v.x * v.x + v.y * v.y + v.z * v.z + v.w * v.w;
        xo[ph * 64 + lane] = make_ushort4(f2bf(v.x), f2bf(v.y), f2bf(v.z), f2bf(v.w));
    }
#pragma unroll
    for (int off = 32; off >= 1; off >>= 1) ss += __shfl_xor(ss, off, 64);
    if (lane == 0) sqn[row] = ss;
}

// ---------------- main: upper-tri 256^2 GEMM + dual-sided fused LSE ----------------
__global__ __launch_bounds__(512, 2) void k_main(const unsigned short* __restrict__ xb,
                                                 const float* __restrict__ sqn,
                                                 const int* __restrict__ y,
                                                 const float* __restrict__ Tp,
                                                 const float* __restrict__ scal,
                                                 float4* __restrict__ part) {
    // 64 KB: [buf][A=0|B=1][256*32 bf16]. Swizzle: granule ^= (row>>1)&3.
    __shared__ __attribute__((aligned(16))) unsigned short lds[2][2][BM * BK];
    float* redR = (float*)&lds[0][0][0];   // [256][4 wc][4]f = 16 KB (overlay)
    float* redC = redR + 4096;             // [256][2 wr][4]f =  8 KB

    // XCD-bijective swizzle (528 = 8*66), then upper-tri decode
    int bid = blockIdx.x;
    int bswz = (bid & 7) * (NBLK / 8) + (bid >> 3);
    int L = bswz, rt = 0, rem = NT;
    while (L >= rem) { L -= rem; --rem; ++rt; }
    int ct = rt + L;
    const bool diag = (rt == ct);

    const int tid = threadIdx.x;
    const int w = tid >> 6, lane = tid & 63;
    const int wr = w >> 2, wc = w & 3;           // 2x4 waves, each 128x64 of C
    const int g = lane >> 4, qq = lane & 15;
    const int rowTile = rt * BM, colTile = ct * BM;

    // staging: per half (128 rows x 32 cols), 1 gload/thread.
    // thread -> row = half*128 + w*16 + (lane>>2); granule = (lane&3) ^ swzkey(row)
    const int srow = w * 16 + (lane >> 2);
    const int colg = (lane & 3) ^ ((lane >> 3) & 3);   // (row>>1)&3 == (lane>>3)&3
    const unsigned short* gA = xb + (size_t)(rowTile + srow) * NDIM + colg * 8;
    const unsigned short* gB = xb + (size_t)(colTile + srow) * NDIM + colg * 8;
    const int ldsoff = w * 16 * BK;                    // wave-uniform dest (+half*4096)

#define STAGE(buf, pn, gptr, half, ke) GLD_LDS16( \
    (gptr) + (size_t)(half) * 128 * NDIM + (ke), \
    &lds[buf][pn][(half) * 128 * BK + ldsoff])

    // ds_read offsets (elements), swizzled: key = (qq>>1)&3
    const int kx = (g ^ ((qq >> 1) & 3)) * 8;
    const int aoff = (wr * 128 + qq) * BK + kx;        // + mi*16*BK
    const int boff = (wc * 64 + qq) * BK + kx;         // + ni*16*BK

    f32x4 acc[8][4];
    const f32x4 zero = {0.f, 0.f, 0.f, 0.f};
#pragma unroll
    for (int i = 0; i < 8; ++i)
#pragma unroll
        for (int j = 0; j < 4; ++j) acc[i][j] = zero;

    // prologue: stage tile 0 into buffer 0
    STAGE(0, 0, gA, 0, 0);
    STAGE(0, 0, gA, 1, 0);
    if (!diag) { STAGE(0, 1, gB, 0, 0); STAGE(0, 1, gB, 1, 0); }

    for (int kt = 0; kt < NKT; ++kt) {
        const int cur = kt & 1;
        const int ke = (kt + 1) * BK;
        // ---- phase 0: stage A(kt+1); publish cur; compute mi 0..3 ----
        if (kt + 1 < NKT) {
            STAGE(cur ^ 1, 0, gA, 0, ke);
            STAGE(cur ^ 1, 0, gA, 1, ke);
            asm volatile("s_waitcnt vmcnt(2)" ::: "memory");  // cur staged; 2 in flight
        } else {
            asm volatile("s_waitcnt vmcnt(0)" ::: "memory");
        }
        __builtin_amdgcn_s_barrier();                         // publish cur
        __builtin_amdgcn_sched_barrier(0);

        const unsigned short* AA = &lds[cur][0][0];
        const unsigned short* BB = diag ? AA : &lds[cur][1][0];
        bf16x8 bf[4];
#pragma unroll
        for (int ni = 0; ni < 4; ++ni)
            bf[ni] = *(const bf16x8*)&BB[boff + ni * 16 * BK];
        {
            bf16x8 af[4];
#pragma unroll
            for (int mi = 0; mi < 4; ++mi)
                af[mi] = *(const bf16x8*)&AA[aoff + mi * 16 * BK];
            __builtin_amdgcn_s_setprio(1);
#pragma unroll
            for (int mi = 0; mi < 4; ++mi)
#pragma unroll
                for (int ni = 0; ni < 4; ++ni)
                    acc[mi][ni] = __builtin_amdgcn_mfma_f32_16x16x32_bf16(
                        af[mi], bf[ni], acc[mi][ni], 0, 0, 0);
            __builtin_amdgcn_s_setprio(0);
        }
        __builtin_amdgcn_s_barrier();                         // rhythm (no drain)
        // ---- phase 1: stage B(kt+1); compute mi 4..7 ----
        if (kt + 1 < NKT && !diag) {
            STAGE(cur ^ 1, 1, gB, 0, ke);
            STAGE(cur ^ 1, 1, gB, 1, ke);
        }
        {
            bf16x8 af[4];
#pragma unroll
            for (int mi = 0; mi < 4; ++mi)
                af[mi] = *(const bf16x8*)&AA[aoff + (mi + 4) * 16 * BK];
            __builtin_amdgcn_s_setprio(1);
#pragma unroll
            for (int mi = 0; mi < 4; ++mi)
#pragma unroll
                for (int ni = 0; ni < 4; ++ni)
                    acc[mi + 4][ni] = __builtin_amdgcn_mfma_f32_16x16x32_bf16(
                        af[mi], bf[ni], acc[mi + 4][ni], 0, 0, 0);
            __builtin_amdgcn_s_setprio(0);
        }
        asm volatile("s_waitcnt lgkmcnt(0)" ::: "memory");    // my reads retired
        __builtin_amdgcn_s_barrier();                         // release cur
    }

    // ---- epilogue (all operand loads AFTER the loop: vmcnt purity) ----
    const float c2 = scal[0] * __builtin_amdgcn_exp2f(Tp[0] * 3.321928094887362f)
                              * 1.4426950408889634f;          // inv_std*10^T*log2e
    float scol[4]; int ycol[4];
#pragma unroll
    for (int ni = 0; ni < 4; ++ni) {
        int C = colTile + wc * 64 + ni * 16 + qq;
        scol[ni] = sqn[C];
        ycol[ni] = y[C];
    }

    // phase 1: acc := s2 in place; label-match bits -> mmA/mmB (64b each)
    unsigned long long mmA = 0ull, mmB = 0ull;
#pragma unroll
    for (int mi = 0; mi < 8; ++mi) {
        float srow4[4]; int yrow4[4];
#pragma unroll
        for (int r = 0; r < 4; ++r) {
            int R = rowTile + wr * 128 + mi * 16 + g * 4 + r;
            srow4[r] = sqn[R];
            yrow4[r] = y[R];
        }
#pragma unroll
        for (int r = 0; r < 4; ++r) {
            const int R = rowTile + wr * 128 + mi * 16 + g * 4 + r;
#pragma unroll
            for (int ni = 0; ni < 4; ++ni) {
                const int C = colTile + wc * 64 + ni * 16 + qq;
                float sq = fmaf(-2.f, acc[mi][ni][r], srow4[r] + scol[ni]);
                sq = fmaxf(sq, 0.f);
                float s2 = -__builtin_amdgcn_sqrtf(sq) * c2;
                if (R == C) s2 = NEG_INF;                     // diagonal mask
                acc[mi][ni][r] = s2;
                unsigned long long bit = (yrow4[r] == ycol[ni]) ? 1ull : 0ull;
                int idx = ((mi & 3) * 4 + r) * 4 + ni;
                if (mi < 4) mmA |= bit << idx; else mmB |= bit << idx;
            }
        }
    }

    // phase 2: row-side partials (in-reg over ni + shfl over 16 qq lanes)
#pragma unroll
    for (int mi = 0; mi < 8; ++mi) {
        unsigned long long mmw = (mi < 4) ? mmA : mmB;
#pragma unroll
        for (int r = 0; r < 4; ++r) {
            float mx = acc[mi][0][r];
#pragma unroll
            for (int ni = 1; ni < 4; ++ni) mx = fmaxf(mx, acc[mi][ni][r]);
#pragma unroll
            for (int off = 1; off <= 8; off <<= 1) mx = fmaxf(mx, __shfl_xor(mx, off, 64));
            float ld = 0.f, ln = 0.f;
#pragma unroll
            for (int ni = 0; ni < 4; ++ni) {
                float e = __builtin_amdgcn_exp2f(acc[mi][ni][r] - mx); // diag -> 0
                ld += e;
                ln += ((mmw >> (((mi & 3) * 4 + r) * 4 + ni)) & 1ull) ? e : 0.f;
            }
#pragma unroll
            for (int off = 1; off <= 8; off <<= 1) {
                ld += __shfl_xor(ld, off, 64);
                ln += __shfl_xor(ln, off, 64);
            }
            if (qq == 0) {
                int lr = wr * 128 + mi * 16 + g * 4 + r;
                redR[(lr * 4 + wc) * 4 + 0] = mx;
                redR[(lr * 4 + wc) * 4 + 1] = ld;
                redR[(lr * 4 + wc) * 4 + 2] = ln;
            }
        }
    }

    // phase 3: col-side partials (in-reg over mi,r + shfl over g), off-diag only
    if (!diag) {
#pragma unroll
        for (int ni = 0; ni < 4; ++ni) {
            float mx = NEG_INF;
#pragma unroll
            for (int mi = 0; mi < 8; ++mi)
#pragma unroll
                for (int r = 0; r < 4; ++r) mx = fmaxf(mx, acc[mi][ni][r]);
            mx = fmaxf(mx, __shfl_xor(mx, 16, 64));
            mx = fmaxf(mx, __shfl_xor(mx, 32, 64));
            float ld = 0.f, ln = 0.f;
#pragma unroll
            for (int mi = 0; mi < 8; ++mi) {
                unsigned long long mmw = (mi < 4) ? mmA : mmB;
#pragma unroll
                for (int r = 0; r < 4; ++r) {
                    float e = __builtin_amdgcn_exp2f(acc[mi][ni][r] - mx);
                    ld += e;
                    ln += ((mmw >> (((mi & 3) * 4 + r) * 4 + ni)) & 1ull) ? e : 0.f;
                }
            }
            ld += __shfl_xor(ld, 16, 64); ld += __shfl_xor(ld, 32, 64);
            ln += __shfl_xor(ln, 16, 64); ln += __shfl_xor(ln, 32, 64);
            if (g == 0) {
                int lc = wc * 64 + ni * 16 + qq;
                redC[(lc * 2 + wr) * 4 + 0] = mx;
                redC[(lc * 2 + wr) * 4 + 1] = ld;
                redC[(lc * 2 + wr) * 4 + 2] = ln;
            }
        }
    }
    __syncthreads();

    if (tid < BM) {
        {
            float M = NEG_INF;
#pragma unroll
            for (int k = 0; k < 4; ++k) M = fmaxf(M, redR[(tid * 4 + k) * 4 + 0]);
            float ld = 0.f, ln = 0.f;
#pragma unroll
            for (int k = 0; k < 4; ++k) {
                float e = __builtin_amdgcn_exp2f(redR[(tid * 4 + k) * 4 + 0] - M);
                ld += redR[(tid * 4 + k) * 4 + 1] * e;
                ln += redR[(tid * 4 + k) * 4 + 2] * e;
            }
            float4 o; o.x = M; o.y = ld; o.z = ln; o.w = 0.f;
            part[(size_t)ct * NROW + rowTile + tid] = o;
        }
        if (!diag) {
            float m0 = redC[(tid * 2 + 0) * 4 + 0], l0 = redC[(tid * 2 + 0) * 4 + 1],
                  n0 = redC[(tid * 2 + 0) * 4 + 2];
            float m1 = redC[(tid * 2 + 1) * 4 + 0], l1 = redC[(tid * 2 + 1) * 4 + 1],
                  n1 = redC[(tid * 2 + 1) * 4 + 2];
            float M = fmaxf(m0, m1);
            float e0 = __builtin_amdgcn_exp2f(m0 - M), e1 = __builtin_amdgcn_exp2f(m1 - M);
            float4 o; o.x = M; o.y = l0 * e0 + l1 * e1; o.z = n0 * e0 + n1 * e1; o.w = 0.f;
            part[(size_t)rt * NROW + colTile + tid] = o;
        }
    }
#undef STAGE
}

// ---------------- combine chunks per row ----------------
__global__ __launch_bounds__(256) void k_rows(const float4* __restrict__ part,
                                              float* __restrict__ rowv) {
    int r = blockIdx.x * 256 + threadIdx.x;
    float M = NEG_INF, L = 0.f, Ln = 0.f;
    for (int ctt = 0; ctt < NT; ++ctt) {
        float4 p = part[(size_t)ctt * NROW + r];
        float m = p.x;                                 // always finite
        if (m > M) {
            float sc = __builtin_amdgcn_exp2f(M - m);  // first iter: exp2(-inf)=0
            L *= sc; Ln *= sc; M = m;
        }
        float s2 = __builtin_amdgcn_exp2f(m - M);
        L  += p.y * s2;
        Ln += p.z * s2;
    }
    float v = (Ln > 0.f) ? (__builtin_amdgcn_logf(Ln) - __builtin_amdgcn_logf(L))
                               * 0.69314718055994530942f
                         : 0.f;
    rowv[r] = v;
}

__global__ __launch_bounds__(256) void k_final(const float* __restrict__ rowv,
                                               float* __restrict__ out) {
    float s = 0.f;
    for (int i = threadIdx.x; i < NROW; i += 256) s += rowv[i];
#pragma unroll
    for (int off = 32; off >= 1; off >>= 1) s += __shfl_xor(s, off, 64);
    __shared__ float sa[4];
    int w = threadIdx.x >> 6, lane = threadIdx.x & 63;
    if (lane == 0) sa[w] = s;
    __syncthreads();
    if (threadIdx.x == 0) out[0] = -((sa[0] + sa[1] + sa[2] + sa[3]) / (float)NROW);
}

extern "C" void kernel_launch(void* const* d_in, const int* in_sizes, int n_in,
                              void* d_out, int out_size, void* d_ws, size_t ws_size,
                              hipStream_t stream) {
    (void)in_sizes; (void)n_in; (void)out_size; (void)ws_size;
    const float* x  = (const float*)d_in[0];
    const int*   y  = (const int*)d_in[1];
    const float* Tp = (const float*)d_in[2];
    float* out = (float*)d_out;

    char* ws = (char*)d_ws;
    double*         part2 = (double*)(ws + WS_PART);
    float*          scal  = (float*)(ws + WS_SCAL);
    unsigned short* xb    = (unsigned short*)(ws + WS_XB);
    float*          sqn   = (float*)(ws + WS_SQN);
    float4*         p4    = (float4*)(ws + WS_P4);
    float*          rowv  = (float*)(ws + WS_ROWV);

    k_stats <<<256, 256, 0, stream>>>(x, part2);
    k_stats2<<<1,   256, 0, stream>>>(part2, scal);
    k_norm  <<<NROW / 4, 256, 0, stream>>>(x, xb, sqn);
    k_main  <<<NBLK, 512, 0, stream>>>(xb, sqn, y, Tp, scal, p4);
    k_rows  <<<NROW / 256, 256, 0, stream>>>(p4, rowv);
    k_final <<<1, 256, 0, stream>>>(rowv, out);
}

// Round 7
// 133.757 us; speedup vs baseline: 1.0081x; 1.0081x over previous
//
#include <hip/hip_runtime.h>

// SNN loss, MI355X. Round 7: m201-style phase schedule at 256x256.
//  Triple-buffered LDS (48KB), prefetch 2 tiles ahead, publish via counted
//  vmcnt(4) once per K-tile; per phase: ds_read issue -> STAGE issue ->
//  barrier -> lgkm(0) -> setprio MFMA -> barrier (reads overlap other waves'
//  MFMA). Granule XOR swizzle on stage-source + read address (T2, verified).
//  Diag blocks stage B as a copy of A (uniform vmcnt, no branches in loop).

#define NROW 8192
#define NDIM 512
#define BM   256
#define BK   32
#define NKT  (NDIM / BK)           // 16 K-tiles
#define NT   (NROW / BM)           // 32 tiles per dim
#define NBLK (NT * (NT + 1) / 2)   // 528 upper-tri blocks

typedef __attribute__((ext_vector_type(8))) short bf16x8;
typedef __attribute__((ext_vector_type(4))) float f32x4;

#define NEG_INF (-__builtin_inff())

// ---- workspace layout (bytes) ----
static const size_t WS_PART = 0;                                   // 256*2 doubles
static const size_t WS_SCAL = 4096;                                // inv_std float
static const size_t WS_XB   = 8192;                                // bf16 x: 8M
static const size_t WS_SQN  = WS_XB + (size_t)NROW * NDIM * 2;     // 8192 floats
static const size_t WS_P4   = WS_SQN + (size_t)NROW * 4;           // 32*8192 float4
static const size_t WS_ROWV = WS_P4 + (size_t)NT * NROW * 16;      // 8192 floats

__device__ __forceinline__ unsigned short f2bf(float f) {
    unsigned int u = __float_as_uint(f);      // finite inputs only
    u += 0x7FFFu + ((u >> 16) & 1u);          // round-to-nearest-even
    return (unsigned short)(u >> 16);
}

#define GLD_LDS16(gp, lp) __builtin_amdgcn_global_load_lds( \
    (const __attribute__((address_space(1))) unsigned int*)(gp), \
    (__attribute__((address_space(3))) unsigned int*)(lp), 16, 0, 0)

// ---------------- stats: sum / sumsq ----------------
__global__ __launch_bounds__(256) void k_stats(const float* __restrict__ x,
                                               double* __restrict__ part) {
    int t = blockIdx.x * 256 + threadIdx.x;
    const float4* x4 = (const float4*)x;
    double s = 0.0, ss = 0.0;
    for (int i = t; i < (NROW * NDIM / 4); i += 256 * 256) {
        float4 v = x4[i];
        double a = v.x, b = v.y, c = v.z, d = v.w;
        s  += (a + b) + (c + d);
        ss += (a * a + b * b) + (c * c + d * d);
    }
#pragma unroll
    for (int off = 32; off >= 1; off >>= 1) {
        s  += __shfl_xor(s, off, 64);
        ss += __shfl_xor(ss, off, 64);
    }
    __shared__ double sa[4], sb[4];
    int w = threadIdx.x >> 6, lane = threadIdx.x & 63;
    if (lane == 0) { sa[w] = s; sb[w] = ss; }
    __syncthreads();
    if (threadIdx.x == 0) {
        part[blockIdx.x * 2]     = sa[0] + sa[1] + sa[2] + sa[3];
        part[blockIdx.x * 2 + 1] = sb[0] + sb[1] + sb[2] + sb[3];
    }
}

__global__ __launch_bounds__(256) void k_stats2(const double* __restrict__ part,
                                                float* __restrict__ scal) {
    int t = threadIdx.x;
    double s = part[t * 2], ss = part[t * 2 + 1];
#pragma unroll
    for (int off = 32; off >= 1; off >>= 1) {
        s  += __shfl_xor(s, off, 64);
        ss += __shfl_xor(ss, off, 64);
    }
    __shared__ double sa[4], sb[4];
    int w = t >> 6, lane = t & 63;
    if (lane == 0) { sa[w] = s; sb[w] = ss; }
    __syncthreads();
    if (t == 0) {
        double S = sa[0] + sa[1] + sa[2] + sa[3];
        double SS = sb[0] + sb[1] + sb[2] + sb[3];
        const double N = (double)NROW * (double)NDIM;
        double var = (SS - S * S / N) / (N - 1.0);   // ddof=1
        scal[0] = (float)(1.0 / sqrt(var));          // inv_std
    }
}

// ---------------- raw x -> bf16 + raw row sqn ----------------
__global__ __launch_bounds__(256) void k_norm(const float* __restrict__ x,
                                              unsigned short* __restrict__ xb,
                                              float* __restrict__ sqn) {
    int w = threadIdx.x >> 6, lane = threadIdx.x & 63;
    int row = blockIdx.x * 4 + w;
    const float4* xr = (const float4*)(x + (size_t)row * NDIM);
    ushort4* xo = (ushort4*)(xb + (size_t)row * NDIM);
    float ss = 0.f;
#pragma unroll
    for (int ph = 0; ph < 2; ++ph) {
        float4 v = xr[ph * 64 + lane];
        ss += v.x * v.x + v.y * v.y + v.z * v.z + v.w * v.w;
        xo[ph * 64 + lane] = make_ushort4(f2bf(v.x), f2bf(v.y), f2bf(v.z), f2bf(v.w));
    }
#pragma unroll
    for (int off = 32; off >= 1; off >>= 1) ss += __shfl_xor(ss, off, 64);
    if (lane == 0) sqn[row] = ss;
}

// ---------------- main: upper-tri 256^2 GEMM + dual-sided fused LSE ----------------
__global__ __launch_bounds__(512, 2) void k_main(const unsigned short* __restrict__ xb,
                                                 const float* __restrict__ sqn,
                                                 const int* __restrict__ y,
                                                 const float* __restrict__ Tp,
                                                 const float* __restrict__ scal,
                                                 float4* __restrict__ part) {
    // 48 KB: [buf3][A=0|B=1][256*32 bf16]. Swizzle: granule ^= (row>>1)&3.
    __shared__ __attribute__((aligned(16))) unsigned short lds[3][2][BM * BK];
    float* redR = (float*)&lds[0][0][0];   // [256][4 wc][4]f = 16 KB (overlay)
    float* redC = redR + 4096;             // [256][2 wr][4]f =  8 KB

    // XCD-bijective swizzle (528 = 8*66), then upper-tri decode
    int bid = blockIdx.x;
    int bswz = (bid & 7) * (NBLK / 8) + (bid >> 3);
    int L = bswz, rt = 0, rem = NT;
    while (L >= rem) { L -= rem; --rem; ++rt; }
    int ct = rt + L;
    const bool diag = (rt == ct);

    const int tid = threadIdx.x;
    const int w = tid >> 6, lane = tid & 63;
    const int wr = w >> 2, wc = w & 3;           // 2x4 waves, each 128x64 of C
    const int g = lane >> 4, qq = lane & 15;
    const int rowTile = rt * BM, colTile = ct * BM;

    // staging: per half (128 rows x 32 cols), 1 gload/thread.
    const int srow = w * 16 + (lane >> 2);
    const int colg = (lane & 3) ^ ((lane >> 3) & 3);   // pre-swizzled source granule
    const unsigned short* gA = xb + (size_t)(rowTile + srow) * NDIM + colg * 8;
    const unsigned short* gB = xb + (size_t)(colTile + srow) * NDIM + colg * 8;
    const int ldsoff = w * 16 * BK;                    // wave-uniform dest

#define STAGE(buf, pn, gptr, half, ke) GLD_LDS16( \
    (gptr) + (size_t)(half) * 128 * NDIM + (ke), \
    &lds[buf][pn][(half) * 128 * BK + ldsoff])

    // ds_read offsets (elements), swizzled: key = (qq>>1)&3
    const int kx = (g ^ ((qq >> 1) & 3)) * 8;
    const int aoff = (wr * 128 + qq) * BK + kx;        // + mi*16*BK
    const int boff = (wc * 64 + qq) * BK + kx;         // + ni*16*BK

    f32x4 acc[8][4];
    const f32x4 zero = {0.f, 0.f, 0.f, 0.f};
#pragma unroll
    for (int i = 0; i < 8; ++i)
#pragma unroll
        for (int j = 0; j < 4; ++j) acc[i][j] = zero;

    // prologue: tiles 0 and 1 in flight; publish tile 0, keep tile 1 flying
    STAGE(0, 0, gA, 0, 0);  STAGE(0, 0, gA, 1, 0);
    STAGE(0, 1, gB, 0, 0);  STAGE(0, 1, gB, 1, 0);
    STAGE(1, 0, gA, 0, BK); STAGE(1, 0, gA, 1, BK);
    STAGE(1, 1, gB, 0, BK); STAGE(1, 1, gB, 1, BK);
    asm volatile("s_waitcnt vmcnt(4)" ::: "memory");   // tile 0 committed
    __builtin_amdgcn_s_barrier();                      // publish buf 0

    int c = 0;                                         // current buffer
    for (int kt = 0; kt < NKT; ++kt) {
        const unsigned short* AA = &lds[c][0][0];
        const unsigned short* BB = &lds[c][1][0];
        int cs = c + 2; if (cs >= 3) cs -= 3;          // stage target buffer
        const int ke = (kt + 2) * BK;
        const bool st = (kt + 2 < NKT);

        // ---- phase 0: reads + A-stage BEFORE barrier (overlap prev MFMA) ----
        bf16x8 bf[4], af[4];
#pragma unroll
        for (int ni = 0; ni < 4; ++ni)
            bf[ni] = *(const bf16x8*)&BB[boff + ni * 16 * BK];
#pragma unroll
        for (int mi = 0; mi < 4; ++mi)
            af[mi] = *(const bf16x8*)&AA[aoff + mi * 16 * BK];
        if (st) { STAGE(cs, 0, gA, 0, ke); STAGE(cs, 0, gA, 1, ke); }
        __builtin_amdgcn_s_barrier();
        asm volatile("s_waitcnt lgkmcnt(0)" ::: "memory");
        __builtin_amdgcn_s_setprio(1);
#pragma unroll
        for (int mi = 0; mi < 4; ++mi)
#pragma unroll
            for (int ni = 0; ni < 4; ++ni)
                acc[mi][ni] = __builtin_amdgcn_mfma_f32_16x16x32_bf16(
                    af[mi], bf[ni], acc[mi][ni], 0, 0, 0);
        __builtin_amdgcn_s_setprio(0);
        __builtin_amdgcn_s_barrier();

        // ---- phase 1: A-half2 reads + B-stage; publish tile kt+1 ----
        bf16x8 af2[4];
#pragma unroll
        for (int mi = 0; mi < 4; ++mi)
            af2[mi] = *(const bf16x8*)&AA[aoff + (mi + 4) * 16 * BK];
        if (st) { STAGE(cs, 1, gB, 0, ke); STAGE(cs, 1, gB, 1, ke); }
        if (kt + 2 < NKT) {
            asm volatile("s_waitcnt vmcnt(4)" ::: "memory");  // tile kt+1 committed
        } else if (kt + 1 < NKT) {
            asm volatile("s_waitcnt vmcnt(0)" ::: "memory");
        }
        __builtin_amdgcn_s_barrier();                  // publish buf (kt+1)%3
        asm volatile("s_waitcnt lgkmcnt(0)" ::: "memory");
        __builtin_amdgcn_s_setprio(1);
#pragma unroll
        for (int mi = 0; mi < 4; ++mi)
#pragma unroll
            for (int ni = 0; ni < 4; ++ni)
                acc[mi + 4][ni] = __builtin_amdgcn_mfma_f32_16x16x32_bf16(
                    af2[mi], bf[ni], acc[mi + 4][ni], 0, 0, 0);
        __builtin_amdgcn_s_setprio(0);
        __builtin_amdgcn_s_barrier();                  // release buf c

        c = c + 1; if (c == 3) c = 0;
    }

    // ---- epilogue (operand loads AFTER the loop: vmcnt purity) ----
    const float c2 = scal[0] * __builtin_amdgcn_exp2f(Tp[0] * 3.321928094887362f)
                              * 1.4426950408889634f;          // inv_std*10^T*log2e
    float scol[4]; int ycol[4];
#pragma unroll
    for (int ni = 0; ni < 4; ++ni) {
        int C = colTile + wc * 64 + ni * 16 + qq;
        scol[ni] = sqn[C];
        ycol[ni] = y[C];
    }

    // phase 1: acc := s2 in place; label-match bits -> mmA/mmB (64b each)
    unsigned long long mmA = 0ull, mmB = 0ull;
#pragma unroll
    for (int mi = 0; mi < 8; ++mi) {
        float srow4[4]; int yrow4[4];
#pragma unroll
        for (int r = 0; r < 4; ++r) {
            int R = rowTile + wr * 128 + mi * 16 + g * 4 + r;
            srow4[r] = sqn[R];
            yrow4[r] = y[R];
        }
#pragma unroll
        for (int r = 0; r < 4; ++r) {
            const int R = rowTile + wr * 128 + mi * 16 + g * 4 + r;
#pragma unroll
            for (int ni = 0; ni < 4; ++ni) {
                const int C = colTile + wc * 64 + ni * 16 + qq;
                float sq = fmaf(-2.f, acc[mi][ni][r], srow4[r] + scol[ni]);
                sq = fmaxf(sq, 0.f);
                float s2 = -__builtin_amdgcn_sqrtf(sq) * c2;
                if (R == C) s2 = NEG_INF;                     // diagonal mask
                acc[mi][ni][r] = s2;
                unsigned long long bit = (yrow4[r] == ycol[ni]) ? 1ull : 0ull;
                int idx = ((mi & 3) * 4 + r) * 4 + ni;
                if (mi < 4) mmA |= bit << idx; else mmB |= bit << idx;
            }
        }
    }

    // phase 2: row-side partials (in-reg over ni + shfl over 16 qq lanes)
#pragma unroll
    for (int mi = 0; mi < 8; ++mi) {
        unsigned long long mmw = (mi < 4) ? mmA : mmB;
#pragma unroll
        for (int r = 0; r < 4; ++r) {
            float mx = acc[mi][0][r];
#pragma unroll
            for (int ni = 1; ni < 4; ++ni) mx = fmaxf(mx, acc[mi][ni][r]);
#pragma unroll
            for (int off = 1; off <= 8; off <<= 1) mx = fmaxf(mx, __shfl_xor(mx, off, 64));
            float ld = 0.f, ln = 0.f;
#pragma unroll
            for (int ni = 0; ni < 4; ++ni) {
                float e = __builtin_amdgcn_exp2f(acc[mi][ni][r] - mx); // diag -> 0
                ld += e;
                ln += ((mmw >> (((mi & 3) * 4 + r) * 4 + ni)) & 1ull) ? e : 0.f;
            }
#pragma unroll
            for (int off = 1; off <= 8; off <<= 1) {
                ld += __shfl_xor(ld, off, 64);
                ln += __shfl_xor(ln, off, 64);
            }
            if (qq == 0) {
                int lr = wr * 128 + mi * 16 + g * 4 + r;
                redR[(lr * 4 + wc) * 4 + 0] = mx;
                redR[(lr * 4 + wc) * 4 + 1] = ld;
                redR[(lr * 4 + wc) * 4 + 2] = ln;
            }
        }
    }

    // phase 3: col-side partials (in-reg over mi,r + shfl over g), off-diag only
    if (!diag) {
#pragma unroll
        for (int ni = 0; ni < 4; ++ni) {
            float mx = NEG_INF;
#pragma unroll
            for (int mi = 0; mi < 8; ++mi)
#pragma unroll
                for (int r = 0; r < 4; ++r) mx = fmaxf(mx, acc[mi][ni][r]);
            mx = fmaxf(mx, __shfl_xor(mx, 16, 64));
            mx = fmaxf(mx, __shfl_xor(mx, 32, 64));
            float ld = 0.f, ln = 0.f;
#pragma unroll
            for (int mi = 0; mi < 8; ++mi) {
                unsigned long long mmw = (mi < 4) ? mmA : mmB;
#pragma unroll
                for (int r = 0; r < 4; ++r) {
                    float e = __builtin_amdgcn_exp2f(acc[mi][ni][r] - mx);
                    ld += e;
                    ln += ((mmw >> (((mi & 3) * 4 + r) * 4 + ni)) & 1ull) ? e : 0.f;
                }
            }
            ld += __shfl_xor(ld, 16, 64); ld += __shfl_xor(ld, 32, 64);
            ln += __shfl_xor(ln, 16, 64); ln += __shfl_xor(ln, 32, 64);
            if (g == 0) {
                int lc = wc * 64 + ni * 16 + qq;
                redC[(lc * 2 + wr) * 4 + 0] = mx;
                redC[(lc * 2 + wr) * 4 + 1] = ld;
                redC[(lc * 2 + wr) * 4 + 2] = ln;
            }
        }
    }
    __syncthreads();

    if (tid < BM) {
        {
            float M = NEG_INF;
#pragma unroll
            for (int k = 0; k < 4; ++k) M = fmaxf(M, redR[(tid * 4 + k) * 4 + 0]);
            float ld = 0.f, ln = 0.f;
#pragma unroll
            for (int k = 0; k < 4; ++k) {
                float e = __builtin_amdgcn_exp2f(redR[(tid * 4 + k) * 4 + 0] - M);
                ld += redR[(tid * 4 + k) * 4 + 1] * e;
                ln += redR[(tid * 4 + k) * 4 + 2] * e;
            }
            float4 o; o.x = M; o.y = ld; o.z = ln; o.w = 0.f;
            part[(size_t)ct * NROW + rowTile + tid] = o;
        }
        if (!diag) {
            float m0 = redC[(tid * 2 + 0) * 4 + 0], l0 = redC[(tid * 2 + 0) * 4 + 1],
                  n0 = redC[(tid * 2 + 0) * 4 + 2];
            float m1 = redC[(tid * 2 + 1) * 4 + 0], l1 = redC[(tid * 2 + 1) * 4 + 1],
                  n1 = redC[(tid * 2 + 1) * 4 + 2];
            float M = fmaxf(m0, m1);
            float e0 = __builtin_amdgcn_exp2f(m0 - M), e1 = __builtin_amdgcn_exp2f(m1 - M);
            float4 o; o.x = M; o.y = l0 * e0 + l1 * e1; o.z = n0 * e0 + n1 * e1; o.w = 0.f;
            part[(size_t)rt * NROW + colTile + tid] = o;
        }
    }
#undef STAGE
}

// ---------------- combine chunks per row ----------------
__global__ __launch_bounds__(256) void k_rows(const float4* __restrict__ part,
                                              float* __restrict__ rowv) {
    int r = blockIdx.x * 256 + threadIdx.x;
    float M = NEG_INF, L = 0.f, Ln = 0.f;
    for (int ctt = 0; ctt < NT; ++ctt) {
        float4 p = part[(size_t)ctt * NROW + r];
        float m = p.x;                                 // always finite
        if (m > M) {
            float sc = __builtin_amdgcn_exp2f(M - m);  // first iter: exp2(-inf)=0
            L *= sc; Ln *= sc; M = m;
        }
        float s2 = __builtin_amdgcn_exp2f(m - M);
        L  += p.y * s2;
        Ln += p.z * s2;
    }
    float v = (Ln > 0.f) ? (__builtin_amdgcn_logf(Ln) - __builtin_amdgcn_logf(L))
                               * 0.69314718055994530942f
                         : 0.f;
    rowv[r] = v;
}

__global__ __launch_bounds__(256) void k_final(const float* __restrict__ rowv,
                                               float* __restrict__ out) {
    float s = 0.f;
    for (int i = threadIdx.x; i < NROW; i += 256) s += rowv[i];
#pragma unroll
    for (int off = 32; off >= 1; off >>= 1) s += __shfl_xor(s, off, 64);
    __shared__ float sa[4];
    int w = threadIdx.x >> 6, lane = threadIdx.x & 63;
    if (lane == 0) sa[w] = s;
    __syncthreads();
    if (threadIdx.x == 0) out[0] = -((sa[0] + sa[1] + sa[2] + sa[3]) / (float)NROW);
}

extern "C" void kernel_launch(void* const* d_in, const int* in_sizes, int n_in,
                              void* d_out, int out_size, void* d_ws, size_t ws_size,
                              hipStream_t stream) {
    (void)in_sizes; (void)n_in; (void)out_size; (void)ws_size;
    const float* x  = (const float*)d_in[0];
    const int*   y  = (const int*)d_in[1];
    const float* Tp = (const float*)d_in[2];
    float* out = (float*)d_out;

    char* ws = (char*)d_ws;
    double*         part2 = (double*)(ws + WS_PART);
    float*          scal  = (float*)(ws + WS_SCAL);
    unsigned short* xb    = (unsigned short*)(ws + WS_XB);
    float*          sqn   = (float*)(ws + WS_SQN);
    float4*         p4    = (float4*)(ws + WS_P4);
    float*          rowv  = (float*)(ws + WS_ROWV);

    k_stats <<<256, 256, 0, stream>>>(x, part2);
    k_stats2<<<1,   256, 0, stream>>>(part2, scal);
    k_norm  <<<NROW / 4, 256, 0, stream>>>(x, xb, sqn);
    k_main  <<<NBLK, 512, 0, stream>>>(xb, sqn, y, Tp, scal, p4);
    k_rows  <<<NROW / 256, 256, 0, stream>>>(p4, rowv);
    k_final <<<1, 256, 0, stream>>>(rowv, out);
}

// Round 8
// 98.808 us; speedup vs baseline: 1.3646x; 1.3537x over previous
//
#include <hip/hip_runtime.h>

// SNN loss, MI355X. Round 8: 128^2 base (R5) + T2 granule swizzle (ported
// from the validated 256^2 scheme) + zero-shfl row epilogue via XOR-swizzled
// LDS transpose + triple-buffered counted-vmcnt(8) K-loop + fused aux chain.
//  k_norm: raw x -> bf16 (ws), per-row sqn + sum (fp32)
//  k_prep: inv_std from row sums (fp64 accumulate), zeroes out[0]
//  k_main: upper-tri 128x128 MFMA tiles of x.x^T (2080 blocks)
//  k_rows: combine partials per row, block atomicAdd of -mean into out

#define NROW 8192
#define NDIM 512
#define BM   128
#define BK   32
#define NKT  (NDIM / BK)           // 16 K-tiles
#define NT   (NROW / BM)           // 64 tiles per dim
#define NBLK (NT * (NT + 1) / 2)   // 2080 upper-tri blocks

typedef __attribute__((ext_vector_type(8))) short bf16x8;
typedef __attribute__((ext_vector_type(4))) float f32x4;

#define NEG_INF (-__builtin_inff())

// ---- workspace layout (bytes) ----
static const size_t WS_SCAL = 4096;                                // inv_std float
static const size_t WS_XB   = 8192;                                // bf16 x: 8M
static const size_t WS_SQN  = WS_XB + (size_t)NROW * NDIM * 2;     // 8192 f32
static const size_t WS_RS   = WS_SQN + (size_t)NROW * 4;           // 8192 f32 row sums
static const size_t WS_P4   = WS_RS + (size_t)NROW * 4;            // 64*8192 float4

__device__ __forceinline__ unsigned short f2bf(float f) {
    unsigned int u = __float_as_uint(f);      // finite inputs only
    u += 0x7FFFu + ((u >> 16) & 1u);          // round-to-nearest-even
    return (unsigned short)(u >> 16);
}

#define GLD_LDS16(gp, lp) __builtin_amdgcn_global_load_lds( \
    (const __attribute__((address_space(1))) unsigned int*)(gp), \
    (__attribute__((address_space(3))) unsigned int*)(lp), 16, 0, 0)

// ---------------- raw x -> bf16 + raw row sqn/sum ----------------
__global__ __launch_bounds__(256) void k_norm(const float* __restrict__ x,
                                              unsigned short* __restrict__ xb,
                                              float* __restrict__ sqn,
                                              float* __restrict__ rsum) {
    int w = threadIdx.x >> 6, lane = threadIdx.x & 63;
    int row = blockIdx.x * 4 + w;
    const float4* xr = (const float4*)(x + (size_t)row * NDIM);
    ushort4* xo = (ushort4*)(xb + (size_t)row * NDIM);
    float ss = 0.f, s1 = 0.f;
#pragma unroll
    for (int ph = 0; ph < 2; ++ph) {
        float4 v = xr[ph * 64 + lane];
        ss += v.x * v.x + v.y * v.y + v.z * v.z + v.w * v.w;
        s1 += (v.x + v.y) + (v.z + v.w);
        xo[ph * 64 + lane] = make_ushort4(f2bf(v.x), f2bf(v.y), f2bf(v.z), f2bf(v.w));
    }
#pragma unroll
    for (int off = 32; off >= 1; off >>= 1) {
        ss += __shfl_xor(ss, off, 64);
        s1 += __shfl_xor(s1, off, 64);
    }
    if (lane == 0) { sqn[row] = ss; rsum[row] = s1; }
}

// ---------------- inv_std + zero the output accumulator ----------------
__global__ __launch_bounds__(256) void k_prep(const float* __restrict__ sqn,
                                              const float* __restrict__ rsum,
                                              float* __restrict__ scal,
                                              float* __restrict__ out) {
    int t = threadIdx.x;
    double s = 0.0, ss = 0.0;
    for (int i = t; i < NROW; i += 256) { s += (double)rsum[i]; ss += (double)sqn[i]; }
#pragma unroll
    for (int off = 32; off >= 1; off >>= 1) {
        s  += __shfl_xor(s, off, 64);
        ss += __shfl_xor(ss, off, 64);
    }
    __shared__ double sa[4], sb[4];
    int w = t >> 6, lane = t & 63;
    if (lane == 0) { sa[w] = s; sb[w] = ss; }
    __syncthreads();
    if (t == 0) {
        double S = sa[0] + sa[1] + sa[2] + sa[3];
        double SS = sb[0] + sb[1] + sb[2] + sb[3];
        const double N = (double)NROW * (double)NDIM;
        double var = (SS - S * S / N) / (N - 1.0);   // ddof=1
        scal[0] = (float)(1.0 / sqrt(var));          // inv_std
        out[0] = 0.f;                                // k_rows accumulates
    }
}

// ---------------- main: upper-tri GEMM + dual-sided fused LSE ----------------
__global__ __launch_bounds__(256, 3) void k_main(const unsigned short* __restrict__ xb,
                                                 const float* __restrict__ sqn,
                                                 const int* __restrict__ y,
                                                 const float* __restrict__ Tp,
                                                 const float* __restrict__ scal,
                                                 float4* __restrict__ part) {
    // 48 KB: [buf3][A|B][128*32 bf16], granule-swizzled.
    __shared__ __attribute__((aligned(16))) unsigned short lds[3][2][BM * BK];
    // epilogue overlays (after final release barrier, all staging retired):
    float4* P    = (float4*)&lds[0][0][0];   // [2 wc][16 qq][64 rows] = 32 KB
    float4* redC = P + 2048;                 // [128 cols][2 wr]       =  4 KB

    // XCD-bijective swizzle (2080 = 8*260), then upper-tri decode
    int bid = blockIdx.x;
    int bswz = (bid & 7) * (NBLK / 8) + (bid >> 3);
    int L = bswz, rt = 0, rem = NT;
    while (L >= rem) { L -= rem; --rem; ++rt; }
    int ct = rt + L;
    const bool diag = (rt == ct);

    const int tid = threadIdx.x;
    const int w = tid >> 6, lane = tid & 63;
    const int wr = w >> 1, wc = w & 1;           // 2x2 waves, 64x64 each
    const int g = lane >> 4, qq = lane & 15;
    const int rowTile = rt * BM, colTile = ct * BM;

    // staging coords: chunk q covers rows [q*16,q*16+16); lane -> row q*16+(l>>2),
    // SOURCE granule pre-swizzled: (l&3)^((l>>3)&3) == (row>>1)&3 within chunk.
    const int q0 = w * 2, q1 = w * 2 + 1;
    const int colg = ((lane & 3) ^ ((lane >> 3) & 3)) * 8;
    const int sr = lane >> 2;
    const unsigned short* gA0 = xb + (size_t)(rowTile + q0 * 16 + sr) * NDIM + colg;
    const unsigned short* gA1 = xb + (size_t)(rowTile + q1 * 16 + sr) * NDIM + colg;
    const unsigned short* gB0 = xb + (size_t)(colTile + q0 * 16 + sr) * NDIM + colg;
    const unsigned short* gB1 = xb + (size_t)(colTile + q1 * 16 + sr) * NDIM + colg;

#define STAGE_T(buf, ke) do { \
    GLD_LDS16(gA0 + (ke), &lds[buf][0][q0 * 512]); \
    GLD_LDS16(gA1 + (ke), &lds[buf][0][q1 * 512]); \
    GLD_LDS16(gB0 + (ke), &lds[buf][1][q0 * 512]); \
    GLD_LDS16(gB1 + (ke), &lds[buf][1][q1 * 512]); } while (0)

    // swizzled read offset: granule g of row r sits at g^((r>>1)&3)
    const int kx = (g ^ ((qq >> 1) & 3)) * 8;
    const int aoff = (wr * 64 + qq) * BK + kx;     // + mi*16*BK
    const int boff = (wc * 64 + qq) * BK + kx;     // + ni*16*BK

    f32x4 acc[4][4];
    const f32x4 zero = {0.f, 0.f, 0.f, 0.f};
#pragma unroll
    for (int i = 0; i < 4; ++i)
#pragma unroll
        for (int j = 0; j < 4; ++j) acc[i][j] = zero;

    // prologue: tiles 0,1 in flight (diag stages B too: pointers coincide)
    STAGE_T(0, 0);
    STAGE_T(1, BK);

    int c = 0;
    for (int kt = 0; kt < NKT; ++kt) {
        if (kt + 2 < NKT) {
            int sb = c + 2; if (sb >= 3) sb -= 3;
            STAGE_T(sb, (kt + 2) * BK);
            asm volatile("s_waitcnt vmcnt(8)" ::: "memory");  // tile kt landed
        } else if (kt + 1 < NKT) {
            asm volatile("s_waitcnt vmcnt(4)" ::: "memory");
        } else {
            asm volatile("s_waitcnt vmcnt(0)" ::: "memory");
        }
        __builtin_amdgcn_s_barrier();                         // publish tile kt

        const unsigned short* AA = &lds[c][0][0];
        const unsigned short* BB = &lds[c][1][0];
        bf16x8 af[4], bfr[4];
#pragma unroll
        for (int mi = 0; mi < 4; ++mi)
            af[mi] = *(const bf16x8*)&AA[aoff + mi * 16 * BK];
#pragma unroll
        for (int ni = 0; ni < 4; ++ni)
            bfr[ni] = *(const bf16x8*)&BB[boff + ni * 16 * BK];
        __builtin_amdgcn_s_setprio(1);
#pragma unroll
        for (int mi = 0; mi < 4; ++mi)
#pragma unroll
            for (int ni = 0; ni < 4; ++ni)
                acc[mi][ni] = __builtin_amdgcn_mfma_f32_16x16x32_bf16(
                    af[mi], bfr[ni], acc[mi][ni], 0, 0, 0);
        __builtin_amdgcn_s_setprio(0);
        asm volatile("s_waitcnt lgkmcnt(0)" ::: "memory");    // my reads retired
        __builtin_amdgcn_s_barrier();                         // release buf c
        c += 1; if (c == 3) c = 0;
    }

    // ---- epilogue ----
    const float c2 = scal[0] * __builtin_amdgcn_exp2f(Tp[0] * 3.321928094887362f)
                             * 1.4426950408889634f;   // inv_std * 10^T * log2e
    float scol[4]; int ycol[4];
#pragma unroll
    for (int ni = 0; ni < 4; ++ni) {
        int C = colTile + wc * 64 + ni * 16 + qq;
        scol[ni] = sqn[C];
        ycol[ni] = y[C];
    }

    // phase 1: acc := s2 in place; label-match bits -> mm0/mm1
    unsigned mm0 = 0, mm1 = 0;
#pragma unroll
    for (int mi = 0; mi < 4; ++mi) {
        float srow4[4]; int yrow4[4];
#pragma unroll
        for (int r = 0; r < 4; ++r) {
            int R = rowTile + wr * 64 + mi * 16 + g * 4 + r;
            srow4[r] = sqn[R];
            yrow4[r] = y[R];
        }
#pragma unroll
        for (int r = 0; r < 4; ++r) {
            const int R = rowTile + wr * 64 + mi * 16 + g * 4 + r;
#pragma unroll
            for (int ni = 0; ni < 4; ++ni) {
                const int C = colTile + wc * 64 + ni * 16 + qq;
                float sq = fmaf(-2.f, acc[mi][ni][r], srow4[r] + scol[ni]);
                sq = fmaxf(sq, 0.f);
                float s2 = -__builtin_amdgcn_sqrtf(sq) * c2;
                if (R == C) s2 = NEG_INF;          // diagonal mask
                acc[mi][ni][r] = s2;
                unsigned bit = (yrow4[r] == ycol[ni]) ? 1u : 0u;
                int idx = ((mi & 1) * 4 + r) * 4 + ni;
                if (mi < 2) mm0 |= bit << idx; else mm1 |= bit << idx;
            }
        }
    }

    // col-side partials (in-reg over mi,r + 2 shfl over g), off-diag only
    if (!diag) {
#pragma unroll
        for (int ni = 0; ni < 4; ++ni) {
            float mx = NEG_INF;
#pragma unroll
            for (int mi = 0; mi < 4; ++mi)
#pragma unroll
                for (int r = 0; r < 4; ++r) mx = fmaxf(mx, acc[mi][ni][r]);
            mx = fmaxf(mx, __shfl_xor(mx, 16, 64));
            mx = fmaxf(mx, __shfl_xor(mx, 32, 64));
            float ld = 0.f, ln = 0.f;
#pragma unroll
            for (int mi = 0; mi < 4; ++mi) {
                unsigned mmw = (mi < 2) ? mm0 : mm1;
#pragma unroll
                for (int r = 0; r < 4; ++r) {
                    float e = __builtin_amdgcn_exp2f(acc[mi][ni][r] - mx);
                    ld += e;
                    ln += ((mmw >> (((mi & 1) * 4 + r) * 4 + ni)) & 1) ? e : 0.f;
                }
            }
            ld += __shfl_xor(ld, 16, 64); ld += __shfl_xor(ld, 32, 64);
            ln += __shfl_xor(ln, 16, 64); ln += __shfl_xor(ln, 32, 64);
            if (g == 0) {
                int lc = wc * 64 + ni * 16 + qq;
                redC[lc * 2 + wr] = make_float4(mx, ld, ln, 0.f);
            }
        }
    }

    // row-side: zero-shfl. Lane-local (over ni) partial -> XOR-swizzled LDS
    // write P[wc][qq][lr^qq]; one wave online-merges 32 partials per row.
#define ROW_WRITE                                                           \
#pragma unroll                                                              \
        for (int mi = 0; mi < 4; ++mi) {                                    \
            unsigned mmw = (mi < 2) ? mm0 : mm1;                            \
_Pragma("unroll")                                                           \
            for (int r = 0; r < 4; ++r) {                                   \
                float m_l = fmaxf(fmaxf(acc[mi][0][r], acc[mi][1][r]),      \
                                  fmaxf(acc[mi][2][r], acc[mi][3][r]));     \
                float ld = 0.f, ln = 0.f;                                   \
_Pragma("unroll")                                                           \
                for (int ni = 0; ni < 4; ++ni) {                            \
                    float e = __builtin_amdgcn_exp2f(acc[mi][ni][r] - m_l); \
                    ld += e;                                                \
                    ln += ((mmw >> (((mi & 1) * 4 + r) * 4 + ni)) & 1) ? e : 0.f; \
                }                                                           \
                int lr = mi * 16 + g * 4 + r;                               \
                P[(wc * 16 + qq) * 64 + (lr ^ qq)] = make_float4(m_l, ld, ln, 0.f); \
            }                                                               \
        }

    if (wr == 0) {
#pragma unroll
        for (int mi = 0; mi < 4; ++mi) {
            unsigned mmw = (mi < 2) ? mm0 : mm1;
#pragma unroll
            for (int r = 0; r < 4; ++r) {
                float m_l = fmaxf(fmaxf(acc[mi][0][r], acc[mi][1][r]),
                                  fmaxf(acc[mi][2][r], acc[mi][3][r]));
                float ld = 0.f, ln = 0.f;
#pragma unroll
                for (int ni = 0; ni < 4; ++ni) {
                    float e = __builtin_amdgcn_exp2f(acc[mi][ni][r] - m_l);
                    ld += e;
                    ln += ((mmw >> (((mi & 1) * 4 + r) * 4 + ni)) & 1) ? e : 0.f;
                }
                int lr = mi * 16 + g * 4 + r;
                P[(wc * 16 + qq) * 64 + (lr ^ qq)] = make_float4(m_l, ld, ln, 0.f);
            }
        }
    }
    __syncthreads();
    if (w == 0) {   // lane = row 0..63 of wr0 half
        float M = NEG_INF, Ls = 0.f, Ln = 0.f;
#pragma unroll
        for (int wcx = 0; wcx < 2; ++wcx)
#pragma unroll
            for (int q = 0; q < 16; ++q) {
                float4 p = P[(wcx * 16 + q) * 64 + (lane ^ q)];
                if (p.x > M) {
                    float s = __builtin_amdgcn_exp2f(M - p.x);
                    Ls *= s; Ln *= s; M = p.x;
                }
                float e = __builtin_amdgcn_exp2f(p.x - M);
                Ls += p.y * e; Ln += p.z * e;
            }
        part[(size_t)ct * NROW + rowTile + lane] = make_float4(M, Ls, Ln, 0.f);
    }
    __syncthreads();
    if (wr == 1) {
#pragma unroll
        for (int mi = 0; mi < 4; ++mi) {
            unsigned mmw = (mi < 2) ? mm0 : mm1;
#pragma unroll
            for (int r = 0; r < 4; ++r) {
                float m_l = fmaxf(fmaxf(acc[mi][0][r], acc[mi][1][r]),
                                  fmaxf(acc[mi][2][r], acc[mi][3][r]));
                float ld = 0.f, ln = 0.f;
#pragma unroll
                for (int ni = 0; ni < 4; ++ni) {
                    float e = __builtin_amdgcn_exp2f(acc[mi][ni][r] - m_l);
                    ld += e;
                    ln += ((mmw >> (((mi & 1) * 4 + r) * 4 + ni)) & 1) ? e : 0.f;
                }
                int lr = mi * 16 + g * 4 + r;
                P[(wc * 16 + qq) * 64 + (lr ^ qq)] = make_float4(m_l, ld, ln, 0.f);
            }
        }
    }
    __syncthreads();
    if (w == 2) {   // lane = row 64..127 (wr1 half)
        float M = NEG_INF, Ls = 0.f, Ln = 0.f;
#pragma unroll
        for (int wcx = 0; wcx < 2; ++wcx)
#pragma unroll
            for (int q = 0; q < 16; ++q) {
                float4 p = P[(wcx * 16 + q) * 64 + (lane ^ q)];
                if (p.x > M) {
                    float s = __builtin_amdgcn_exp2f(M - p.x);
                    Ls *= s; Ln *= s; M = p.x;
                }
                float e = __builtin_amdgcn_exp2f(p.x - M);
                Ls += p.y * e; Ln += p.z * e;
            }
        part[(size_t)ct * NROW + rowTile + 64 + lane] = make_float4(M, Ls, Ln, 0.f);
    }
    if (!diag) {
        __syncthreads();
        if (tid < BM) {
            float4 a = redC[tid * 2 + 0], b = redC[tid * 2 + 1];
            float M = fmaxf(a.x, b.x);
            float e0 = __builtin_amdgcn_exp2f(a.x - M), e1 = __builtin_amdgcn_exp2f(b.x - M);
            part[(size_t)rt * NROW + colTile + tid] =
                make_float4(M, a.y * e0 + b.y * e1, a.z * e0 + b.z * e1, 0.f);
        }
    }
#undef STAGE_T
}

// ---------------- combine chunks per row + final mean ----------------
__global__ __launch_bounds__(256) void k_rows(const float4* __restrict__ part,
                                              float* __restrict__ out) {
    int r = blockIdx.x * 256 + threadIdx.x;
    float M = NEG_INF, Ls = 0.f, Ln = 0.f;
    for (int ctt = 0; ctt < NT; ++ctt) {
        float4 p = part[(size_t)ctt * NROW + r];
        if (p.x > M) {
            float sc = __builtin_amdgcn_exp2f(M - p.x);
            Ls *= sc; Ln *= sc; M = p.x;
        }
        float s2 = __builtin_amdgcn_exp2f(p.x - M);
        Ls += p.y * s2;
        Ln += p.z * s2;
    }
    float v = (Ln > 0.f) ? (__builtin_amdgcn_logf(Ln) - __builtin_amdgcn_logf(Ls))
                               * 0.69314718055994530942f
                         : 0.f;
#pragma unroll
    for (int off = 32; off >= 1; off >>= 1) v += __shfl_xor(v, off, 64);
    __shared__ float sa[4];
    int w = threadIdx.x >> 6, lane = threadIdx.x & 63;
    if (lane == 0) sa[w] = v;
    __syncthreads();
    if (threadIdx.x == 0)
        atomicAdd(out, -((sa[0] + sa[1] + sa[2] + sa[3]) / (float)NROW));
}

extern "C" void kernel_launch(void* const* d_in, const int* in_sizes, int n_in,
                              void* d_out, int out_size, void* d_ws, size_t ws_size,
                              hipStream_t stream) {
    (void)in_sizes; (void)n_in; (void)out_size; (void)ws_size;
    const float* x  = (const float*)d_in[0];
    const int*   y  = (const int*)d_in[1];
    const float* Tp = (const float*)d_in[2];
    float* out = (float*)d_out;

    char* ws = (char*)d_ws;
    float*          scal = (float*)(ws + WS_SCAL);
    unsigned short* xb   = (unsigned short*)(ws + WS_XB);
    float*          sqn  = (float*)(ws + WS_SQN);
    float*          rsum = (float*)(ws + WS_RS);
    float4*         p4   = (float4*)(ws + WS_P4);

    k_norm <<<NROW / 4, 256, 0, stream>>>(x, xb, sqn, rsum);
    k_prep <<<1, 256, 0, stream>>>(sqn, rsum, scal, out);
    k_main <<<NBLK, 256, 0, stream>>>(xb, sqn, y, Tp, scal, p4);
    k_rows <<<NROW / 256, 256, 0, stream>>>(p4, out);
}